// Round 4
// baseline (297.804 us; speedup 1.0000x reference)
//
#include <hip/hip_runtime.h>

// GCN 3-layer + MLP head.
// Round-4 change: fuse aggregation + next GEMM into one kernel (h lives only
// in LDS; 51MB/layer of h round-trip traffic eliminated; gather-phase blocks
// overlap GEMM-phase blocks across the grid). Final kernel chains
// agg3 -> @Wo1+bo1 -> @Wo2+bo2 with t in LDS. scan3 folded into consumers.
// Pipeline (8 launches):
//   k_gemm1_hist: g1 = bf16(x@W1), fused with dst-histogram
//   scan1/scan2 ; scatter ; finalize  -> csr, rp, dis
//   k_fused<0>(g1, b1, W2) -> g2 ; k_fused<0>(g2, b2, W3) -> g3
//   k_fused<1>(g3, b3, Wo1,bo1, Wo2,bo2) -> out
// Math: h_i = relu(dis_i*( sum_{e:dst=i} dis_src*graw_src + dis_i*graw_i )+b)
// graw = h@W stored bf16; all accumulation fp32.

#define DHID 128
#define NBUK 256   // dst buckets
#define NBLK 196   // edge-chunk blocks (NBUK*NBLK = 50176 scan elements)

static __device__ __forceinline__ unsigned short f2bf(float f) {
  unsigned int u = __float_as_uint(f);
  u += 0x7fffu + ((u >> 16) & 1u);  // round-to-nearest-even
  return (unsigned short)(u >> 16);
}
static __device__ __forceinline__ float bf_lo(unsigned int v) {
  return __uint_as_float(v << 16);
}
static __device__ __forceinline__ float bf_hi(unsigned int v) {
  return __uint_as_float(v & 0xffff0000u);
}

// ---------------- scan ----------------

__global__ __launch_bounds__(256) void k_scan1(const int* __restrict__ in,
                                               int* __restrict__ out,
                                               int* __restrict__ blk, int Mtot) {
  __shared__ int s[256];
  int tid = threadIdx.x;
  int i = blockIdx.x * 256 + tid;
  int v = (i < Mtot) ? in[i] : 0;
  s[tid] = v;
  __syncthreads();
  for (int off = 1; off < 256; off <<= 1) {
    int t = (tid >= off) ? s[tid - off] : 0;
    __syncthreads();
    s[tid] += t;
    __syncthreads();
  }
  if (i < Mtot) out[i] = s[tid] - v;  // exclusive within block
  if (tid == 255) blk[blockIdx.x] = s[255];
}

__global__ void k_scan2(int* blk, int n) {  // n <= 256
  __shared__ int s[256];
  int tid = threadIdx.x;
  int v = (tid < n) ? blk[tid] : 0;
  s[tid] = v;
  __syncthreads();
  for (int off = 1; off < 256; off <<= 1) {
    int t = (tid >= off) ? s[tid - off] : 0;
    __syncthreads();
    s[tid] += t;
    __syncthreads();
  }
  if (tid < n) blk[tid] = s[tid] - v;  // exclusive
}

// ---------------- GEMM body: [64,128] @ [128,128] -> bf16 (hist kernel) ----

__device__ __forceinline__ void gemm128_body0(const float* __restrict__ H,
                                              const float* __restrict__ W,
                                              void* __restrict__ out, int M,
                                              int row0) {
  __shared__ float4 Hs[64 * 32];  // 32 KB
  int tid = threadIdx.x;
  const float4* H4 = (const float4*)H;
#pragma unroll
  for (int i = 0; i < 8; i++) {
    int slot = tid + i * 256;  // 0..2047
    int r = slot >> 5, c4 = slot & 31;
    int gr = row0 + r;
    Hs[slot] = (gr < M) ? H4[(size_t)gr * 32 + c4] : make_float4(0.f, 0.f, 0.f, 0.f);
  }
  __syncthreads();

  int c4 = tid & 31;
  int r0 = (tid >> 5) * 8;
  const float4* W4 = (const float4*)W;
  float4 acc[8];
#pragma unroll
  for (int r = 0; r < 8; r++) acc[r] = make_float4(0.f, 0.f, 0.f, 0.f);

  for (int k4 = 0; k4 < 32; k4++) {
    float4 w0 = W4[(k4 * 4 + 0) * 32 + c4];
    float4 w1 = W4[(k4 * 4 + 1) * 32 + c4];
    float4 w2 = W4[(k4 * 4 + 2) * 32 + c4];
    float4 w3 = W4[(k4 * 4 + 3) * 32 + c4];
#pragma unroll
    for (int r = 0; r < 8; r++) {
      float4 h = Hs[(r0 + r) * 32 + k4];
      acc[r].x = fmaf(h.w, w3.x, fmaf(h.z, w2.x, fmaf(h.y, w1.x, fmaf(h.x, w0.x, acc[r].x))));
      acc[r].y = fmaf(h.w, w3.y, fmaf(h.z, w2.y, fmaf(h.y, w1.y, fmaf(h.x, w0.y, acc[r].y))));
      acc[r].z = fmaf(h.w, w3.z, fmaf(h.z, w2.z, fmaf(h.y, w1.z, fmaf(h.x, w0.z, acc[r].z))));
      acc[r].w = fmaf(h.w, w3.w, fmaf(h.z, w2.w, fmaf(h.y, w1.w, fmaf(h.x, w0.w, acc[r].w))));
    }
  }

#pragma unroll
  for (int r = 0; r < 8; r++) {
    int gr = row0 + r0 + r;
    if (gr < M) {
      ushort4 o;
      o.x = f2bf(acc[r].x); o.y = f2bf(acc[r].y);
      o.z = f2bf(acc[r].z); o.w = f2bf(acc[r].w);
      ((ushort4*)out)[(size_t)gr * 32 + c4] = o;
    }
  }
}

// layer-1 GEMM fused with sort pass 1 (dst histogram).
__global__ __launch_bounds__(256) void k_gemm1_hist(const float* __restrict__ H,
                                                    const float* __restrict__ W,
                                                    void* __restrict__ out, int M,
                                                    int nG, const int* __restrict__ ei,
                                                    int E, int EPB, int NPB,
                                                    int* __restrict__ Hist) {
  if ((int)blockIdx.x >= nG) {
    __shared__ int hs[NBUK];
    int tid = threadIdx.x;
    int j = (int)blockIdx.x - nG;
    hs[tid] = 0;
    __syncthreads();
    int e0 = j * EPB;
    int e1 = min(e0 + EPB, E);
    for (int e = e0 + tid; e < e1; e += 256) {
      int d = ei[E + e];
      atomicAdd(&hs[d / NPB], 1);
    }
    __syncthreads();
    Hist[tid * NBLK + j] = hs[tid];
    return;
  }
  gemm128_body0(H, W, out, M, (int)blockIdx.x * 64);
}

// sort pass 2: bucket-grouped scatter (scan3 folded: S local + blk).
__global__ __launch_bounds__(256) void k_scatter(const int* __restrict__ ei, int E,
                                                 int EPB, int NPB,
                                                 const int* __restrict__ S,
                                                 const int* __restrict__ blk,
                                                 int2* __restrict__ sorted) {
  __shared__ int run[NBUK];
  int tid = threadIdx.x;
  int j = blockIdx.x;
  int idx = tid * NBLK + j;
  run[tid] = S[idx] + blk[idx >> 8];
  __syncthreads();
  int e0 = j * EPB;
  int e1 = min(e0 + EPB, E);
  for (int e = e0 + tid; e < e1; e += 256) {
    int s = ei[e];
    int d = ei[E + e];
    int slot = atomicAdd(&run[d / NPB], 1);
    sorted[slot] = make_int2(s, d);
  }
}

// sort pass 3: per-bucket finalize -> rp, dis, csr.
__global__ __launch_bounds__(256) void k_finalize(const int2* __restrict__ sorted,
                                                  const int* __restrict__ S,
                                                  const int* __restrict__ blk,
                                                  int E, int M, int NPB,
                                                  int* __restrict__ rp,
                                                  float* __restrict__ dis,
                                                  int* __restrict__ csr) {
  __shared__ int cnt[256];
  __shared__ int sc[256];
  int b = blockIdx.x;
  int tid = threadIdx.x;
  int node0 = b * NPB;
  int i0 = b * NBLK;
  int start = S[i0] + blk[i0 >> 8];
  int end;
  if (b == NBUK - 1) end = E;
  else {
    int i1 = i0 + NBLK;
    end = S[i1] + blk[i1 >> 8];
  }
  cnt[tid] = 0;
  __syncthreads();
  for (int i = start + tid; i < end; i += 256) {
    atomicAdd(&cnt[sorted[i].y - node0], 1);
  }
  __syncthreads();
  int v = cnt[tid];
  sc[tid] = v;
  __syncthreads();
  for (int off = 1; off < 256; off <<= 1) {
    int t = (tid >= off) ? sc[tid - off] : 0;
    __syncthreads();
    sc[tid] += t;
    __syncthreads();
  }
  int lrp = sc[tid] - v;
  int node = node0 + tid;
  if (tid < NPB && node < M) {
    rp[node] = start + lrp;
    dis[node] = rsqrtf((float)v + 1.0f);
  }
  if (b == NBUK - 1 && tid == 0) rp[M] = E;
  __syncthreads();
  cnt[tid] = lrp;
  __syncthreads();
  for (int i = start + tid; i < end; i += 256) {
    int2 p = sorted[i];
    int slot = atomicAdd(&cnt[p.y - node0], 1);
    csr[start + slot] = p.x;
  }
}

// ---------------- fused aggregation + GEMM ----------------
// Phase A: 4 waves x 16 nodes: h_row = relu(dis_i*(sum dis_s*g_s + dis_i*g_i)+bagg)
//          -> LDS tile Hs[64][128] fp32
// Phase B (FINAL=0): g_out = bf16(Hs @ W)           [out: ushort, M x 128]
// Phase B (FINAL=1): t = Hs@W + bW (t -> LDS); out = t@W2 + bW2  [out: float, M x 64]

template <int FINAL>
__global__ __launch_bounds__(256) void k_fused(const unsigned short* __restrict__ gin,
                                               const int* __restrict__ csr,
                                               const int* __restrict__ rp,
                                               const float* __restrict__ dis,
                                               const float* __restrict__ bagg,
                                               const float* __restrict__ W,
                                               const float* __restrict__ bW,
                                               const float* __restrict__ W2,
                                               const float* __restrict__ bW2,
                                               void* __restrict__ out, int M) {
  __shared__ float4 Hs[64 * 32];  // 32 KB
  float2* Hs2 = (float2*)Hs;
  int tid = threadIdx.x;
  int lane = tid & 63;
  int w = tid >> 6;
  int row0 = blockIdx.x * 64;
  const unsigned int* g1 = (const unsigned int*)gin;

  // ---- phase A: aggregate 16 nodes per wave ----
  for (int jj = 0; jj < 16; jj++) {
    int j = w * 16 + jj;
    int i = row0 + j;
    float rx = 0.f, ry = 0.f;
    if (i < M) {
      float di = dis[i];
      unsigned int self = g1[(size_t)i * 64 + lane];
      float ax = di * bf_lo(self);
      float ay = di * bf_hi(self);
      int start = rp[i], end = rp[i + 1];
      for (int base = start; base < end; base += 64) {
        int n = end - base;
        if (n > 64) n = 64;
        int idx = 0;
        float dsv = 0.f;
        if (lane < n) {
          idx = csr[base + lane];
          dsv = dis[idx];
        }
        int jx = 0;
        for (; jx + 4 <= n; jx += 4) {
          int s0 = __shfl(idx, jx, 64);
          int s1 = __shfl(idx, jx + 1, 64);
          int s2 = __shfl(idx, jx + 2, 64);
          int s3 = __shfl(idx, jx + 3, 64);
          float d0 = __shfl(dsv, jx, 64);
          float d1 = __shfl(dsv, jx + 1, 64);
          float d2 = __shfl(dsv, jx + 2, 64);
          float d3 = __shfl(dsv, jx + 3, 64);
          unsigned int v0 = g1[(size_t)s0 * 64 + lane];
          unsigned int v1 = g1[(size_t)s1 * 64 + lane];
          unsigned int v2 = g1[(size_t)s2 * 64 + lane];
          unsigned int v3 = g1[(size_t)s3 * 64 + lane];
          ax = fmaf(d0, bf_lo(v0), ax);
          ay = fmaf(d0, bf_hi(v0), ay);
          ax = fmaf(d1, bf_lo(v1), ax);
          ay = fmaf(d1, bf_hi(v1), ay);
          ax = fmaf(d2, bf_lo(v2), ax);
          ay = fmaf(d2, bf_hi(v2), ay);
          ax = fmaf(d3, bf_lo(v3), ax);
          ay = fmaf(d3, bf_hi(v3), ay);
        }
        for (; jx < n; ++jx) {
          int s0 = __shfl(idx, jx, 64);
          float d0 = __shfl(dsv, jx, 64);
          unsigned int v = g1[(size_t)s0 * 64 + lane];
          ax = fmaf(d0, bf_lo(v), ax);
          ay = fmaf(d0, bf_hi(v), ay);
        }
      }
      float2 b = ((const float2*)bagg)[lane];
      rx = fmaxf(fmaf(di, ax, b.x), 0.f);
      ry = fmaxf(fmaf(di, ay, b.y), 0.f);
    }
    Hs2[j * 64 + lane] = make_float2(rx, ry);  // row j, cols 2*lane..2*lane+1
  }
  __syncthreads();

  // ---- phase B1: Hs @ W ----
  int c4 = tid & 31;
  int r0 = (tid >> 5) * 8;
  const float4* W4 = (const float4*)W;
  float4 acc[8];
#pragma unroll
  for (int r = 0; r < 8; r++) acc[r] = make_float4(0.f, 0.f, 0.f, 0.f);

  for (int k4 = 0; k4 < 32; k4++) {
    float4 w0 = W4[(k4 * 4 + 0) * 32 + c4];
    float4 w1 = W4[(k4 * 4 + 1) * 32 + c4];
    float4 w2 = W4[(k4 * 4 + 2) * 32 + c4];
    float4 w3 = W4[(k4 * 4 + 3) * 32 + c4];
#pragma unroll
    for (int r = 0; r < 8; r++) {
      float4 h = Hs[(r0 + r) * 32 + k4];
      acc[r].x = fmaf(h.w, w3.x, fmaf(h.z, w2.x, fmaf(h.y, w1.x, fmaf(h.x, w0.x, acc[r].x))));
      acc[r].y = fmaf(h.w, w3.y, fmaf(h.z, w2.y, fmaf(h.y, w1.y, fmaf(h.x, w0.y, acc[r].y))));
      acc[r].z = fmaf(h.w, w3.z, fmaf(h.z, w2.z, fmaf(h.y, w1.z, fmaf(h.x, w0.z, acc[r].z))));
      acc[r].w = fmaf(h.w, w3.w, fmaf(h.z, w2.w, fmaf(h.y, w1.w, fmaf(h.x, w0.w, acc[r].w))));
    }
  }

  if (!FINAL) {
#pragma unroll
    for (int r = 0; r < 8; r++) {
      int gr = row0 + r0 + r;
      if (gr < M) {
        ushort4 o;
        o.x = f2bf(acc[r].x); o.y = f2bf(acc[r].y);
        o.z = f2bf(acc[r].z); o.w = f2bf(acc[r].w);
        ((ushort4*)out)[(size_t)gr * 32 + c4] = o;
      }
    }
  } else {
    // t = acc + bW -> back into Hs (all Hs reads are done; barrier first)
    float4 bv = ((const float4*)bW)[c4];
    __syncthreads();
#pragma unroll
    for (int r = 0; r < 8; r++) {
      float4 v = acc[r];
      v.x += bv.x; v.y += bv.y; v.z += bv.z; v.w += bv.w;
      Hs[(r0 + r) * 32 + c4] = v;
    }
    __syncthreads();

    // ---- phase B2: t @ W2 + bW2 -> out fp32 [M][64] ----
    int c42 = tid & 15;
    int r02 = (tid >> 4) * 4;
    const float4* V4 = (const float4*)W2;
    float4 a2[4];
#pragma unroll
    for (int r = 0; r < 4; r++) a2[r] = make_float4(0.f, 0.f, 0.f, 0.f);

    for (int k4 = 0; k4 < 32; k4++) {
      float4 w0 = V4[(k4 * 4 + 0) * 16 + c42];
      float4 w1 = V4[(k4 * 4 + 1) * 16 + c42];
      float4 w2v = V4[(k4 * 4 + 2) * 16 + c42];
      float4 w3 = V4[(k4 * 4 + 3) * 16 + c42];
#pragma unroll
      for (int r = 0; r < 4; r++) {
        float4 h = Hs[(r02 + r) * 32 + k4];
        a2[r].x = fmaf(h.w, w3.x, fmaf(h.z, w2v.x, fmaf(h.y, w1.x, fmaf(h.x, w0.x, a2[r].x))));
        a2[r].y = fmaf(h.w, w3.y, fmaf(h.z, w2v.y, fmaf(h.y, w1.y, fmaf(h.x, w0.y, a2[r].y))));
        a2[r].z = fmaf(h.w, w3.z, fmaf(h.z, w2v.z, fmaf(h.y, w1.z, fmaf(h.x, w0.z, a2[r].z))));
        a2[r].w = fmaf(h.w, w3.w, fmaf(h.z, w2v.w, fmaf(h.y, w1.w, fmaf(h.x, w0.w, a2[r].w))));
      }
    }
    float4 b2v = ((const float4*)bW2)[c42];
#pragma unroll
    for (int r = 0; r < 4; r++) {
      int gr = row0 + r02 + r;
      if (gr < M) {
        float4 v = a2[r];
        v.x += b2v.x; v.y += b2v.y; v.z += b2v.z; v.w += b2v.w;
        ((float4*)out)[(size_t)gr * 16 + c42] = v;
      }
    }
  }
}

// ---------------- launch ----------------

extern "C" void kernel_launch(void* const* d_in, const int* in_sizes, int n_in,
                              void* d_out, int out_size, void* d_ws, size_t ws_size,
                              hipStream_t stream) {
  const float* x = (const float*)d_in[0];
  const int* ei = (const int*)d_in[1];
  const float* W1 = (const float*)d_in[2];
  const float* b1 = (const float*)d_in[3];
  const float* W2 = (const float*)d_in[4];
  const float* b2 = (const float*)d_in[5];
  const float* W3 = (const float*)d_in[6];
  const float* b3 = (const float*)d_in[7];
  const float* Wo1 = (const float*)d_in[8];
  const float* bo1 = (const float*)d_in[9];
  const float* Wo2 = (const float*)d_in[10];
  const float* bo2 = (const float*)d_in[11];
  float* out = (float*)d_out;

  int M = in_sizes[0] / DHID;  // 50000
  int E = in_sizes[1] / 2;     // 800000

  int NPB = (M + NBUK - 1) / NBUK;  // nodes per bucket (196)
  int EPB = (E + NBLK - 1) / NBLK;  // edges per sort block
  int SCN = NBUK * NBLK;            // 50176

  // workspace layout (~41.4 MB peak)
  char* ws = (char*)d_ws;
  float* dis = (float*)(ws + 0);                        // M floats
  int* rp = (int*)(ws + (1ull << 20));                  // M+1 ints
  int* Hist = (int*)(ws + (2ull << 20));                // SCN ints
  int* S = (int*)(ws + (3ull << 20));                   // SCN ints
  int* blk = (int*)(ws + (4ull << 20));                 // <=256 ints
  int* csr = (int*)(ws + (5ull << 20));                 // E ints (3.2 MB)
  unsigned short* gA = (unsigned short*)(ws + (9ull << 20));   // M*128 bf16 (12.8 MB)
  unsigned short* gB = (unsigned short*)(ws + (22ull << 20));  // M*128 bf16 (12.8 MB)
  int2* sorted = (int2*)(ws + (35ull << 20));           // E int2 (6.4 MB)

  int gG = (M + 63) / 64;  // 782

  // layer-1 GEMM fused with sort pass 1
  k_gemm1_hist<<<gG + NBLK, 256, 0, stream>>>(x, W1, gA, M, gG, ei, E, EPB, NPB, Hist);
  // scan Hist
  k_scan1<<<NBLK, 256, 0, stream>>>(Hist, S, blk, SCN);
  k_scan2<<<1, 256, 0, stream>>>(blk, NBLK);
  // sort pass 2 + 3 (scan3 folded in)
  k_scatter<<<NBLK, 256, 0, stream>>>(ei, E, EPB, NPB, S, blk, sorted);
  k_finalize<<<NBUK, 256, 0, stream>>>(sorted, S, blk, E, M, NPB, rp, dis, csr);

  // fused layers
  k_fused<0><<<gG, 256, 0, stream>>>(gA, csr, rp, dis, b1, W2, nullptr, nullptr,
                                     nullptr, gB, M);
  k_fused<0><<<gG, 256, 0, stream>>>(gB, csr, rp, dis, b2, W3, nullptr, nullptr,
                                     nullptr, gA, M);
  k_fused<1><<<gG, 256, 0, stream>>>(gA, csr, rp, dis, b3, Wo1, bo1, Wo2, bo2,
                                     out, M);
}